// Round 12
// baseline (51.089 us; speedup 1.0000x reference)
//
#include <hip/hip_runtime.h>
#include <hip/hip_bf16.h>

#define ALPHA 0.2f
#define LOG2E 1.4426950408889634f

typedef __attribute__((ext_vector_type(8))) short bf16x8;
typedef __attribute__((ext_vector_type(4))) float f32x4;
typedef __attribute__((ext_vector_type(4))) int i32x4;

__device__ __forceinline__ int cvt_pk_bf16(float lo, float hi) {
    int r;
    asm("v_cvt_pk_bf16_f32 %0, %1, %2" : "=v"(r) : "v"(lo), "v"(hi));
    return r;
}

// ---------------------------------------------------------------------------
// Kernel A (verified round-11, unchanged): Wh = h @ W (fp32), si2/sj2 scaled
// by log2e, Wh emitted PRE-FRAGMENTED for the MFMA B operand:
//   WhF[((b*64 + jc)*4 + ob)*512 + lane*8 + e] = bf16(Wh[j][o]),
//   j = jc*32 + (lane>>4)*8 + e, o = ob*16 + (lane&15)
// ---------------------------------------------------------------------------
__global__ __launch_bounds__(256) void gat_precompute(
    const float* __restrict__ h, const float* __restrict__ W,
    const float* __restrict__ a, unsigned short* __restrict__ WhF,
    float* __restrict__ si2, float* __restrict__ sj2)
{
    __shared__ float h_lds[32][128];
    __shared__ float wh_lds[32][65];   // +1 pad
    const int tid  = threadIdx.x;
    const int lane = tid & 63;
    const int wave = tid >> 6;
    const long long row0 = (long long)blockIdx.x * 32;

    {
        const float4* s4 = (const float4*)(h + row0 * 128);
        #pragma unroll
        for (int i = 0; i < 4; ++i) {
            int idx = tid + i * 256;
            float4 v = s4[idx];
            *(float4*)&h_lds[idx >> 5][(idx & 31) * 4] = v;
        }
    }
    __syncthreads();

    const float a1 = a[lane];
    const float a2 = a[64 + lane];
    float acc[8];
    #pragma unroll
    for (int r = 0; r < 8; ++r) acc[r] = 0.0f;

    for (int f = 0; f < 128; f += 4) {
        const float w0 = W[(f+0)*64 + lane];
        const float w1 = W[(f+1)*64 + lane];
        const float w2 = W[(f+2)*64 + lane];
        const float w3 = W[(f+3)*64 + lane];
        #pragma unroll
        for (int r = 0; r < 8; ++r) {
            const float4 hv = *(const float4*)&h_lds[wave*8 + r][f];
            acc[r] = fmaf(hv.x, w0, acc[r]);
            acc[r] = fmaf(hv.y, w1, acc[r]);
            acc[r] = fmaf(hv.z, w2, acc[r]);
            acc[r] = fmaf(hv.w, w3, acc[r]);
        }
    }

    #pragma unroll
    for (int r = 0; r < 8; ++r) {
        const int rr = wave*8 + r;
        wh_lds[rr][lane] = acc[r];
        float s1 = acc[r] * a1;
        float s2 = acc[r] * a2;
        #pragma unroll
        for (int off = 32; off > 0; off >>= 1) {
            s1 += __shfl_xor(s1, off);
            s2 += __shfl_xor(s2, off);
        }
        if (lane == 0) {
            si2[row0 + rr] = s1 * LOG2E;
            sj2[row0 + rr] = s2 * LOG2E;
        }
    }
    __syncthreads();

    // fragment write: tid = ob*64 + lane
    const long long b  = row0 >> 11;
    const int jcb  = (int)((row0 & 2047) >> 5);   // j-chunk within batch
    const int ob   = tid >> 6;
    const int ln   = tid & 63;
    const int ar   = ln & 15;
    const int gg   = ln >> 4;
    i32x4 pk;
    #pragma unroll
    for (int k = 0; k < 4; ++k)
        pk[k] = cvt_pk_bf16(wh_lds[gg*8 + 2*k    ][ob*16 + ar],
                            wh_lds[gg*8 + 2*k + 1][ob*16 + ar]);
    *(i32x4*)(WhF + ((b*64 + jcb)*4 + ob)*512 + ln*8) = pk;
}

// ---------------------------------------------------------------------------
// Kernel B: fused masked-softmax attention, ZERO barriers / ZERO LDS in the
// main loop. Each wave owns a private 512-j quarter; all operands go straight
// to VGPRs: adj per-lane A-fragment loads (2x dwordx4 from row i0+arow, 100%
// line utilization), sj per-lane, WhF coalesced pre-fragmented B-fragments.
// 2-ahead software pipeline (3 rotating slots, fully unrolled -> registers);
// the compiler inserts counted vmcnt at first use -- no barrier ever drains
// the prefetch (the flaw that pinned rounds 5-11 at 45-48us).
// p = exp2(max(Ci+sj, 0.2*sj+Di)) * (adj>0), fixed row max (lrelu monotone).
// Epilogue (only LDS use): round-11 verified combine.
// ---------------------------------------------------------------------------
__global__ __launch_bounds__(256) void gat_attention(
    const int* __restrict__ adj, const unsigned short* __restrict__ WhF,
    const float* __restrict__ si2, const float* __restrict__ sj2,
    float* __restrict__ out)
{
    __shared__ char ldsbuf[16640];   // epilogue only: accb 16K + lb 256B
    const int tid  = threadIdx.x;
    const int lane = tid & 63;
    const int wave = tid >> 6;
    const int b    = blockIdx.x & 7;                 // batch -> XCD affinity
    const int i0   = (int)((blockIdx.x >> 3) << 4);  // 16-row i-tile
    const int arow = lane & 15;
    const int g    = lane >> 4;
    const long long bN = (long long)b * 2048;

    // per-lane operand streams
    const int*   aptr = adj + (bN + i0 + arow)*2048 + wave*512 + g*8;
    const float* sjq  = sj2 + bN + wave*512 + g*8;
    const unsigned short* fbase =
        WhF + ((long long)(b*64 + wave*16) * 4) * 512 + lane*8;

    // ---- per-batch sjmax (block-redundant, once) ----
    const float* sjb = sj2 + bN;
    float mx = -INFINITY;
    #pragma unroll 4
    for (int i = 0; i < 32; ++i) mx = fmaxf(mx, sjb[lane + i*64]);
    #pragma unroll
    for (int off = 32; off > 0; off >>= 1) mx = fmaxf(mx, __shfl_xor(mx, off));

    const float si_r = si2[bN + i0 + arow];        // P-row = arow
    const float u0f  = si_r + mx;
    const float m2   = fmaxf(u0f, ALPHA * u0f);    // fixed row max (log2 dom)
    const float Ci   = si_r - m2;
    const float Di   = ALPHA * si_r - m2;

    f32x4 accf[4];
    #pragma unroll
    for (int ob = 0; ob < 4; ++ob) accf[ob] = (f32x4){0.f,0.f,0.f,0.f};
    f32x4 accl = (f32x4){0.f,0.f,0.f,0.f};
    bf16x8 ones;
    #pragma unroll
    for (int k = 0; k < 8; ++k) ones[k] = (short)0x3F80;   // bf16 1.0

    // rotating prefetch slots (constant-indexed after full unroll -- rule #20)
    i32x4 A0[3], A1[3];
    f32x4 S0[3], S1[3];
    bf16x8 cb0, cb1, cb2, cb3, nb0, nb1, nb2, nb3;

    #define LOADA(SLOT, STEP) { \
        A0[SLOT] = *(const i32x4*)(aptr + (STEP)*32); \
        A1[SLOT] = *(const i32x4*)(aptr + (STEP)*32 + 4); \
        S0[SLOT] = *(const f32x4*)(sjq + (STEP)*32); \
        S1[SLOT] = *(const f32x4*)(sjq + (STEP)*32 + 4); \
    }
    #define LOADB(D0, D1, D2, D3, STEP) { \
        D0 = *(const bf16x8*)(fbase + ((STEP)*4 + 0)*512); \
        D1 = *(const bf16x8*)(fbase + ((STEP)*4 + 1)*512); \
        D2 = *(const bf16x8*)(fbase + ((STEP)*4 + 2)*512); \
        D3 = *(const bf16x8*)(fbase + ((STEP)*4 + 3)*512); \
    }

    // ---- prologue: 2 steps of adj/sj + 1 step of WhF in flight ----
    LOADA(0, 0);
    LOADA(1, 1);
    LOADB(cb0, cb1, cb2, cb3, 0);

    // ---- barrier-free main loop (fully unrolled) ----
    #pragma unroll
    for (int st = 0; st < 16; ++st) {
        if (st < 14) LOADA((st + 2) % 3, st + 2);
        if (st < 15) LOADB(nb0, nb1, nb2, nb3, st + 1);

        const i32x4 cA0 = A0[st % 3];
        const i32x4 cA1 = A1[st % 3];
        const f32x4 cS0 = S0[st % 3];
        const f32x4 cS1 = S1[st % 3];

        float p[8];
        #pragma unroll
        for (int e = 0; e < 4; ++e) {
            float pe = __builtin_amdgcn_exp2f(
                fmaxf(Ci + cS0[e], fmaf(ALPHA, cS0[e], Di)));
            p[e] = (cA0[e] > 0) ? pe : 0.0f;
        }
        #pragma unroll
        for (int e = 0; e < 4; ++e) {
            float pe = __builtin_amdgcn_exp2f(
                fmaxf(Ci + cS1[e], fmaf(ALPHA, cS1[e], Di)));
            p[4+e] = (cA1[e] > 0) ? pe : 0.0f;
        }
        i32x4 pk_;
        pk_[0] = cvt_pk_bf16(p[0], p[1]);
        pk_[1] = cvt_pk_bf16(p[2], p[3]);
        pk_[2] = cvt_pk_bf16(p[4], p[5]);
        pk_[3] = cvt_pk_bf16(p[6], p[7]);
        const bf16x8 pa = __builtin_bit_cast(bf16x8, pk_);

        accl    = __builtin_amdgcn_mfma_f32_16x16x32_bf16(pa, ones, accl,    0, 0, 0);
        accf[0] = __builtin_amdgcn_mfma_f32_16x16x32_bf16(pa, cb0, accf[0], 0, 0, 0);
        accf[1] = __builtin_amdgcn_mfma_f32_16x16x32_bf16(pa, cb1, accf[1], 0, 0, 0);
        accf[2] = __builtin_amdgcn_mfma_f32_16x16x32_bf16(pa, cb2, accf[2], 0, 0, 0);
        accf[3] = __builtin_amdgcn_mfma_f32_16x16x32_bf16(pa, cb3, accf[3], 0, 0, 0);

        cb0 = nb0; cb1 = nb1; cb2 = nb2; cb3 = nb3;
    }

    // ---- epilogue (round-11 verified): combine 4 quarters, divide, store --
    float* accb = (float*)ldsbuf;             // [4 wave][16 i][64 o] = 16KB
    float* lb   = (float*)(ldsbuf + 16384);   // [4 wave][16 i]
    #pragma unroll
    for (int ob = 0; ob < 4; ++ob)
        #pragma unroll
        for (int reg = 0; reg < 4; ++reg)
            accb[(wave*16 + g*4 + reg)*64 + ob*16 + arow] = accf[ob][reg];
    if (arow == 0) {
        #pragma unroll
        for (int reg = 0; reg < 4; ++reg)
            lb[wave*16 + g*4 + reg] = accl[reg];
    }
    __syncthreads();

    const int r  = tid >> 4;                  // 0..15
    const int c0 = (tid & 15) * 4;
    const float L = lb[r] + lb[16 + r] + lb[32 + r] + lb[48 + r];
    const float inv = 1.0f / L;
    float4 v;
    v.x = (accb[r*64 + c0 + 0] + accb[(16+r)*64 + c0 + 0]
         + accb[(32+r)*64 + c0 + 0] + accb[(48+r)*64 + c0 + 0]) * inv;
    v.y = (accb[r*64 + c0 + 1] + accb[(16+r)*64 + c0 + 1]
         + accb[(32+r)*64 + c0 + 1] + accb[(48+r)*64 + c0 + 1]) * inv;
    v.z = (accb[r*64 + c0 + 2] + accb[(16+r)*64 + c0 + 2]
         + accb[(32+r)*64 + c0 + 2] + accb[(48+r)*64 + c0 + 2]) * inv;
    v.w = (accb[r*64 + c0 + 3] + accb[(16+r)*64 + c0 + 3]
         + accb[(32+r)*64 + c0 + 3] + accb[(48+r)*64 + c0 + 3]) * inv;
    *(float4*)(out + (bN + i0 + r)*64 + c0) = v;
}

// ---------------------------------------------------------------------------
// ws layout: WhF 2MB | si2 64KB | sj2 64KB
// ---------------------------------------------------------------------------
extern "C" void kernel_launch(void* const* d_in, const int* in_sizes, int n_in,
                              void* d_out, int out_size, void* d_ws, size_t ws_size,
                              hipStream_t stream) {
    const float* h   = (const float*)d_in[0];
    const int*   adj = (const int*)d_in[1];
    const float* W   = (const float*)d_in[2];
    const float* a   = (const float*)d_in[3];
    float* out = (float*)d_out;

    unsigned short* WhF = (unsigned short*)d_ws;                // 2 MB
    float* si2 = (float*)((char*)d_ws + (size_t)16384*64*2);
    float* sj2 = si2 + 16384;

    gat_precompute<<<512, 256, 0, stream>>>(h, W, a, WhF, si2, sj2);
    gat_attention<<<1024, 256, 0, stream>>>(adj, WhF, si2, sj2, out);
}